// Round 10
// baseline (310.680 us; speedup 1.0000x reference)
//
#include <hip/hip_runtime.h>
#include <math.h>

// Problem constants (B,C,H,W) = (8,128,256,256), Ch = 64
constexpr int Bn = 8, Cn = 128, ChN = 64, Hn = 256, Wn = 256;
constexpr long long HWn  = (long long)Hn * Wn;   // 65536
constexpr long long CHWn = (long long)Cn * HWn;  // 8388608

typedef short  s16x8  __attribute__((ext_vector_type(8)));
typedef __bf16 bf16x8 __attribute__((ext_vector_type(8)));
typedef float  f32x4  __attribute__((ext_vector_type(4)));

static __device__ __forceinline__ unsigned short f2bf(float f) {
    union { float f; unsigned u; } v; v.f = f;
    unsigned r = (v.u + 0x7FFFu + ((v.u >> 16) & 1u)) >> 16;
    return (unsigned short)r;
}
static __device__ __forceinline__ bf16x8 tobf(s16x8 s) {
    bf16x8 r; __builtin_memcpy(&r, &s, 16); return r;
}

// Prep: pack w1 (64x128 f32) into MFMA A-fragments (bf16), and transpose w2.
__global__ void prep(const float* __restrict__ w1, const float* __restrict__ w2,
                     uint4* __restrict__ af, float* __restrict__ w2t) {
    int idx = blockIdx.x * 256 + threadIdx.x;
    if (idx < 1024) {
        int lane = idx & 63, kb = (idx >> 6) & 3, ot = idx >> 8;
        int row   = ot * 16 + (lane & 15);
        int kbase = kb * 32 + ((lane >> 4) & 3) * 8;
        const float* src = w1 + row * Cn + kbase;
        unsigned short b[8];
        #pragma unroll
        for (int t = 0; t < 8; ++t) b[t] = f2bf(src[t]);
        uint4 r;
        r.x = (unsigned)b[0] | ((unsigned)b[1] << 16);
        r.y = (unsigned)b[2] | ((unsigned)b[3] << 16);
        r.z = (unsigned)b[4] | ((unsigned)b[5] << 16);
        r.w = (unsigned)b[6] | ((unsigned)b[7] << 16);
        af[idx] = r;
    } else if (idx < 1024 + ChN * 4) {
        int t = idx - 1024;               // t = o*4 + k
        w2t[t] = w2[(t & 3) * ChN + (t >> 2)];
    }
}

__device__ __forceinline__ float softplus_f(float x) {
    return fmaxf(x, 0.0f) + log1pf(expf(-fabsf(x)));
}

// ============================ Kernel A: w-field ============================
// One 16-px chunk per wave (MFMA 16x16x32, M=o, N=px, K=128), 4 waves/block.
// Writes w4[p] = {wu,wd,wl,wr} (float4), p = b*HWn + i*Wn + j.
__global__ __launch_bounds__(256) void wfield(
    const float* __restrict__ wi,
    const uint4* __restrict__ af,
    const float* __restrict__ w2t,
    const float* __restrict__ b1,
    const float* __restrict__ b2,
    float4* __restrict__ w4)
{
    const int tid  = threadIdx.x;
    const int wv   = tid >> 6;
    const int lane = tid & 63;
    const int l15  = lane & 15;
    const int lg   = lane >> 4;

    const int chunk = blockIdx.x * 4 + wv;     // 0..32767
    const int p0    = chunk * 16;              // first pixel (b-i-j linear)
    const int bb    = p0 >> 16;                // batch (16 | 65536: no straddle)
    const int rem   = p0 & (int)(HWn - 1);     // i*Wn + j

    // wi address for (bb, c, rem): bb*CHWn + c*HWn + rem   (round-9 bug: the
    // bb*CHWn term was omitted -> wrong field for b>=1)
    const float* wip = wi + (size_t)bb * CHWn + rem + l15;

    f32x4 acc[4];
    #pragma unroll
    for (int ot = 0; ot < 4; ++ot)
        acc[ot] = *(const f32x4*)(b1 + ot * 16 + lg * 4);   // b1 folded in C

    #pragma unroll
    for (int kb = 0; kb < 4; ++kb) {
        float xb[8];
        #pragma unroll
        for (int t = 0; t < 8; ++t)
            xb[t] = wip[(size_t)(kb * 32 + lg * 8 + t) * HWn];
        s16x8 bs;
        #pragma unroll
        for (int t = 0; t < 8; ++t) bs[t] = (short)f2bf(xb[t]);
        bf16x8 bfrag = tobf(bs);
        #pragma unroll
        for (int ot = 0; ot < 4; ++ot) {
            s16x8 as = ((const s16x8*)af)[(ot * 4 + kb) * 64 + lane];
            acc[ot] = __builtin_amdgcn_mfma_f32_16x16x32_bf16(
                          tobf(as), bfrag, acc[ot], 0, 0, 0);
        }
    }

    float a0 = 0.f, a1 = 0.f, a2 = 0.f, a3 = 0.f;
    #pragma unroll
    for (int ot = 0; ot < 4; ++ot) {
        #pragma unroll
        for (int r = 0; r < 4; ++r) {
            int o = ot * 16 + lg * 4 + r;
            float hv = fmaxf(acc[ot][r], 0.f);
            const float4 w4v = ((const float4*)w2t)[o];
            a0 = fmaf(w4v.x, hv, a0);
            a1 = fmaf(w4v.y, hv, a1);
            a2 = fmaf(w4v.z, hv, a2);
            a3 = fmaf(w4v.w, hv, a3);
        }
    }
    a0 += __shfl_xor(a0, 16); a0 += __shfl_xor(a0, 32);
    a1 += __shfl_xor(a1, 16); a1 += __shfl_xor(a1, 32);
    a2 += __shfl_xor(a2, 16); a2 += __shfl_xor(a2, 32);
    a3 += __shfl_xor(a3, 16); a3 += __shfl_xor(a3, 32);

    if (lg == 0) {
        float4 r;
        r.x = softplus_f(a0 + b2[0]);
        r.y = softplus_f(a1 + b2[1]);
        r.z = softplus_f(a2 + b2[2]);
        r.w = softplus_f(a3 + b2[3]);
        w4[p0 + l15] = r;
    }
}

// ============================ Kernel B: stencil ============================
// Block = 32 rows of one (b,c) plane; wave = 8 contiguous rows (one row per
// iter: 64 lanes x float4 = 256 px). Grid = 8 batches x 128 c x 8 segs = 8192
// (round-9 bug: launched 2048 -> 3/4 of out never written).
// Halo rows are same-plane (L1/L2 hit); w4 slice per batch = 1 MB, L2-resident
// on its XCD (blockIdx&7 = batch).
__global__ __launch_bounds__(256) void stencil(
    const float* __restrict__ u,
    const float4* __restrict__ w4,
    float* __restrict__ out)
{
    const int bb   = blockIdx.x & 7;          // batch == XCD partition
    const int rest = blockIdx.x >> 3;         // 0..1023
    const int c    = rest >> 3;               // 0..127
    const int seg  = rest & 7;                // 0..7 (32-row segment)
    const int wv   = threadIdx.x >> 6;
    const int lane = threadIdx.x & 63;

    const size_t plane = ((size_t)bb * Cn + c) * HWn;
    const float*  up0 = u   + plane;
    float*        op0 = out + plane;
    const float4* wp  = w4 + (size_t)bb * HWn;   // [i*Wn + j] for this batch

    const int i0 = seg * 32 + wv * 8;
    const int j4 = lane * 4;

    const float4 z4 = {0.f, 0.f, 0.f, 0.f};
    #pragma unroll 2
    for (int r = 0; r < 8; ++r) {
        const int i = i0 + r;
        const float* rp = up0 + (size_t)i * Wn + j4;

        float4 ctr = *(const float4*)rp;
        float4 up4 = (i > 0)      ? *(const float4*)(rp - Wn) : z4;
        float4 dn4 = (i < Hn - 1) ? *(const float4*)(rp + Wn) : z4;

        const float4* wrow = wp + (size_t)i * Wn + j4;  // one float4 per pixel
        float4 w0 = wrow[0], w1v = wrow[1], w2v = wrow[2], w3v = wrow[3];

        float lw = __shfl(ctr.w, lane - 1);
        float rw = __shfl(ctr.x, lane + 1);
        float lfx = (lane == 0)  ? 0.f : lw;
        float rtw = (lane == 63) ? 0.f : rw;

        float ws0 = (w0.x + w0.y) + (w0.z + w0.w);
        float ws1 = (w1v.x + w1v.y) + (w1v.z + w1v.w);
        float ws2 = (w2v.x + w2v.y) + (w2v.z + w2v.w);
        float ws3 = (w3v.x + w3v.y) + (w3v.z + w3v.w);

        float4 res;
        res.x = fmaf(w0.x,  up4.x, fmaf(w0.y,  dn4.x, fmaf(w0.z,  lfx,   fmaf(w0.w,  ctr.y, -ws0 * ctr.x))));
        res.y = fmaf(w1v.x, up4.y, fmaf(w1v.y, dn4.y, fmaf(w1v.z, ctr.x, fmaf(w1v.w, ctr.z, -ws1 * ctr.y))));
        res.z = fmaf(w2v.x, up4.z, fmaf(w2v.y, dn4.z, fmaf(w2v.z, ctr.y, fmaf(w2v.w, ctr.w, -ws2 * ctr.z))));
        res.w = fmaf(w3v.x, up4.w, fmaf(w3v.y, dn4.w, fmaf(w3v.z, ctr.z, fmaf(w3v.w, rtw,   -ws3 * ctr.w))));
        *(float4*)(op0 + (size_t)i * Wn + j4) = res;
    }
}

extern "C" void kernel_launch(void* const* d_in, const int* in_sizes, int n_in,
                              void* d_out, int out_size, void* d_ws, size_t ws_size,
                              hipStream_t stream) {
    const float* u  = (const float*)d_in[0];
    const float* wi = (const float*)d_in[1];
    const float* w1 = (const float*)d_in[2];
    const float* b1 = (const float*)d_in[3];
    const float* w2 = (const float*)d_in[4];
    const float* b2 = (const float*)d_in[5];
    float* out = (float*)d_out;

    uint4*  af  = (uint4*)d_ws;                      // 16 KB
    float*  w2t = (float*)((char*)d_ws + 16384);     // 1 KB
    float4* w4  = (float4*)((char*)d_ws + 17408);    // 8 MB

    prep<<<5, 256, 0, stream>>>(w1, w2, af, w2t);
    wfield<<<8192, 256, 0, stream>>>(wi, af, w2t, b1, b2, w4);
    stencil<<<8192, 256, 0, stream>>>(u, w4, out);
}

// Round 12
// 264.990 us; speedup vs baseline: 1.1724x; 1.1724x over previous
//
#include <hip/hip_runtime.h>
#include <math.h>

// Problem constants (B,C,H,W) = (8,128,256,256), Ch = 64
constexpr int Bn = 8, Cn = 128, ChN = 64, Hn = 256, Wn = 256;
constexpr long long HWn  = (long long)Hn * Wn;   // 65536
constexpr long long CHWn = (long long)Cn * HWn;  // 8388608

typedef short  s16x8  __attribute__((ext_vector_type(8)));
typedef __bf16 bf16x8 __attribute__((ext_vector_type(8)));
typedef float  f32x4  __attribute__((ext_vector_type(4)));

static __device__ __forceinline__ unsigned short f2bf(float f) {
    union { float f; unsigned u; } v; v.f = f;
    unsigned r = (v.u + 0x7FFFu + ((v.u >> 16) & 1u)) >> 16;
    return (unsigned short)r;
}
static __device__ __forceinline__ bf16x8 tobf(s16x8 s) {
    bf16x8 r; __builtin_memcpy(&r, &s, 16); return r;
}

// Prep: pack w1 (64x128 f32) into MFMA A-fragments (bf16), and transpose w2.
__global__ void prep(const float* __restrict__ w1, const float* __restrict__ w2,
                     uint4* __restrict__ af, float* __restrict__ w2t) {
    int idx = blockIdx.x * 256 + threadIdx.x;
    if (idx < 1024) {
        int lane = idx & 63, kb = (idx >> 6) & 3, ot = idx >> 8;
        int row   = ot * 16 + (lane & 15);
        int kbase = kb * 32 + ((lane >> 4) & 3) * 8;
        const float* src = w1 + row * Cn + kbase;
        unsigned short b[8];
        #pragma unroll
        for (int t = 0; t < 8; ++t) b[t] = f2bf(src[t]);
        uint4 r;
        r.x = (unsigned)b[0] | ((unsigned)b[1] << 16);
        r.y = (unsigned)b[2] | ((unsigned)b[3] << 16);
        r.z = (unsigned)b[4] | ((unsigned)b[5] << 16);
        r.w = (unsigned)b[6] | ((unsigned)b[7] << 16);
        af[idx] = r;
    } else if (idx < 1024 + ChN * 4) {
        int t = idx - 1024;               // t = o*4 + k
        w2t[t] = w2[(t & 3) * ChN + (t >> 2)];
    }
}

__device__ __forceinline__ float softplus_f(float x) {
    return fmaxf(x, 0.0f) + log1pf(expf(-fabsf(x)));
}

// ============================ Kernel A: w-field ============================
// One 16-px chunk per wave (MFMA 16x16x32), 4 waves/block. Writes the four
// direction weights as SoA planes wu/wd/wl/wr (p = b*HWn + i*Wn + j) so the
// stencil reads them lane-contiguously. All 32 wi loads issued before any
// pack/MFMA (max MLP).
__global__ __launch_bounds__(256) void wfield(
    const float* __restrict__ wi,
    const uint4* __restrict__ af,
    const float* __restrict__ w2t,
    const float* __restrict__ b1,
    const float* __restrict__ b2,
    float* __restrict__ wu_f, float* __restrict__ wd_f,
    float* __restrict__ wl_f, float* __restrict__ wr_f)
{
    const int tid  = threadIdx.x;
    const int wv   = tid >> 6;
    const int lane = tid & 63;
    const int l15  = lane & 15;
    const int lg   = lane >> 4;

    const int chunk = blockIdx.x * 4 + wv;     // 0..32767
    const int p0    = chunk * 16;              // first pixel (b-i-j linear)
    const int bb    = p0 >> 16;                // batch
    const int rem   = p0 & (int)(HWn - 1);     // i*Wn + j

    const float* wip = wi + (size_t)bb * CHWn + rem + l15;

    // All 32 channel-strided loads in flight before any dependent work.
    float xb[32];
    #pragma unroll
    for (int kb = 0; kb < 4; ++kb)
        #pragma unroll
        for (int t = 0; t < 8; ++t)
            xb[kb * 8 + t] = wip[(size_t)(kb * 32 + lg * 8 + t) * HWn];

    f32x4 acc[4];
    #pragma unroll
    for (int ot = 0; ot < 4; ++ot)
        acc[ot] = *(const f32x4*)(b1 + ot * 16 + lg * 4);   // b1 folded in C

    #pragma unroll
    for (int kb = 0; kb < 4; ++kb) {
        s16x8 bs;
        #pragma unroll
        for (int t = 0; t < 8; ++t) bs[t] = (short)f2bf(xb[kb * 8 + t]);
        bf16x8 bfrag = tobf(bs);
        #pragma unroll
        for (int ot = 0; ot < 4; ++ot) {
            s16x8 as = ((const s16x8*)af)[(ot * 4 + kb) * 64 + lane];
            acc[ot] = __builtin_amdgcn_mfma_f32_16x16x32_bf16(
                          tobf(as), bfrag, acc[ot], 0, 0, 0);
        }
    }

    float a0 = 0.f, a1 = 0.f, a2 = 0.f, a3 = 0.f;
    #pragma unroll
    for (int ot = 0; ot < 4; ++ot) {
        #pragma unroll
        for (int r = 0; r < 4; ++r) {
            int o = ot * 16 + lg * 4 + r;
            float hv = fmaxf(acc[ot][r], 0.f);
            const float4 w4v = ((const float4*)w2t)[o];
            a0 = fmaf(w4v.x, hv, a0);
            a1 = fmaf(w4v.y, hv, a1);
            a2 = fmaf(w4v.z, hv, a2);
            a3 = fmaf(w4v.w, hv, a3);
        }
    }
    a0 += __shfl_xor(a0, 16); a0 += __shfl_xor(a0, 32);
    a1 += __shfl_xor(a1, 16); a1 += __shfl_xor(a1, 32);
    a2 += __shfl_xor(a2, 16); a2 += __shfl_xor(a2, 32);
    a3 += __shfl_xor(a3, 16); a3 += __shfl_xor(a3, 32);

    if (lg == 0) {
        const int p = p0 + l15;
        wu_f[p] = softplus_f(a0 + b2[0]);
        wd_f[p] = softplus_f(a1 + b2[1]);
        wl_f[p] = softplus_f(a2 + b2[2]);
        wr_f[p] = softplus_f(a3 + b2[3]);
    }
}

// ============================ Kernel B: stencil ============================
// Wave = 4-row strip of one (b,c) plane. The 6 u-rows (i0-1..i0+4, halo
// shared: dn of row r == ctr of row r+1) are ALL loaded upfront -> ~22KB of
// independent loads in flight per wave before any waitcnt (round-10: per-row
// load->wait->store serialization left <3KB in flight -> 2 TB/s).
// Grid = 8 batch x 128 c x 16 seg = 16384; blk&7 = batch = XCD partition.
__global__ __launch_bounds__(256) void stencil2(
    const float* __restrict__ u,
    const float* __restrict__ wu_f, const float* __restrict__ wd_f,
    const float* __restrict__ wl_f, const float* __restrict__ wr_f,
    float* __restrict__ out)
{
    const int bb   = blockIdx.x & 7;
    const int rest = blockIdx.x >> 3;         // 0..2047
    const int seg  = rest & 15;               // 16-row segment
    const int c    = rest >> 4;               // 0..127
    const int wv   = threadIdx.x >> 6;
    const int lane = threadIdx.x & 63;

    const size_t plane = ((size_t)bb * Cn + c) * HWn;
    const int i0 = seg * 16 + wv * 4;         // first output row of this wave
    const int j4 = lane * 4;

    const float*  up0 = u + plane + j4;
    const size_t  wb  = (size_t)bb * HWn + j4;
    const float4  z4  = {0.f, 0.f, 0.f, 0.f};

    // 6 u-rows upfront (boundary rows -> 0)
    float4 R[6];
    #pragma unroll
    for (int t = 0; t < 6; ++t) {
        const int i = i0 - 1 + t;
        R[t] = (i >= 0 && i < Hn) ? *(const float4*)(up0 + (size_t)i * Wn) : z4;
    }
    // 4 w-rows x 4 dirs, lane-contiguous
    float4 WUr[4], WDr[4], WLr[4], WRr[4];
    #pragma unroll
    for (int r = 0; r < 4; ++r) {
        const size_t wo = wb + (size_t)(i0 + r) * Wn;
        WUr[r] = *(const float4*)(wu_f + wo);
        WDr[r] = *(const float4*)(wd_f + wo);
        WLr[r] = *(const float4*)(wl_f + wo);
        WRr[r] = *(const float4*)(wr_f + wo);
    }

    float* po = out + plane + j4;
    #pragma unroll
    for (int r = 0; r < 4; ++r) {
        float4 ctr = R[r + 1], up4 = R[r], dn4 = R[r + 2];
        float4 WU = WUr[r], WD = WDr[r], WL = WLr[r], WR = WRr[r];

        float lw = __shfl(ctr.w, lane - 1);
        float rw = __shfl(ctr.x, lane + 1);
        float lfx = (lane == 0)  ? 0.f : lw;
        float rtw = (lane == 63) ? 0.f : rw;

        float4 WS;
        WS.x = (WU.x + WD.x) + (WL.x + WR.x);
        WS.y = (WU.y + WD.y) + (WL.y + WR.y);
        WS.z = (WU.z + WD.z) + (WL.z + WR.z);
        WS.w = (WU.w + WD.w) + (WL.w + WR.w);

        float4 res;
        res.x = fmaf(WU.x, up4.x, fmaf(WD.x, dn4.x, fmaf(WL.x, lfx,   fmaf(WR.x, ctr.y, -WS.x * ctr.x))));
        res.y = fmaf(WU.y, up4.y, fmaf(WD.y, dn4.y, fmaf(WL.y, ctr.x, fmaf(WR.y, ctr.z, -WS.y * ctr.y))));
        res.z = fmaf(WU.z, up4.z, fmaf(WD.z, dn4.z, fmaf(WL.z, ctr.y, fmaf(WR.z, ctr.w, -WS.z * ctr.z))));
        res.w = fmaf(WU.w, up4.w, fmaf(WD.w, dn4.w, fmaf(WL.w, ctr.z, fmaf(WR.w, rtw,   -WS.w * ctr.w))));

        // __builtin_nontemporal_store needs a clang ext-vector, not
        // HIP_vector_type (round-11 compile error) -> bit-cast to f32x4.
        f32x4 resv;
        __builtin_memcpy(&resv, &res, 16);
        __builtin_nontemporal_store(resv, (f32x4*)(po + (size_t)(i0 + r) * Wn));
    }
}

extern "C" void kernel_launch(void* const* d_in, const int* in_sizes, int n_in,
                              void* d_out, int out_size, void* d_ws, size_t ws_size,
                              hipStream_t stream) {
    const float* u  = (const float*)d_in[0];
    const float* wi = (const float*)d_in[1];
    const float* w1 = (const float*)d_in[2];
    const float* b1 = (const float*)d_in[3];
    const float* w2 = (const float*)d_in[4];
    const float* b2 = (const float*)d_in[5];
    float* out = (float*)d_out;

    uint4* af  = (uint4*)d_ws;                       // 16 KB
    float* w2t = (float*)((char*)d_ws + 16384);      // 1 KB (pad to 17408)
    float* wu_f = (float*)((char*)d_ws + 17408);     // 4 x 2 MB SoA planes
    float* wd_f = wu_f + Bn * HWn;
    float* wl_f = wd_f + Bn * HWn;
    float* wr_f = wl_f + Bn * HWn;

    prep<<<5, 256, 0, stream>>>(w1, w2, af, w2t);
    wfield<<<8192, 256, 0, stream>>>(wi, af, w2t, b1, b2, wu_f, wd_f, wl_f, wr_f);
    stencil2<<<16384, 256, 0, stream>>>(u, wu_f, wd_f, wl_f, wr_f, out);
}

// Round 13
// 257.673 us; speedup vs baseline: 1.2057x; 1.0284x over previous
//
#include <hip/hip_runtime.h>
#include <math.h>

// Problem constants (B,C,H,W) = (8,128,256,256), Ch = 64
constexpr int Bn = 8, Cn = 128, ChN = 64, Hn = 256, Wn = 256;
constexpr long long HWn  = (long long)Hn * Wn;   // 65536
constexpr long long CHWn = (long long)Cn * HWn;  // 8388608

typedef short  s16x8  __attribute__((ext_vector_type(8)));
typedef __bf16 bf16x8 __attribute__((ext_vector_type(8)));
typedef float  f32x4  __attribute__((ext_vector_type(4)));

static __device__ __forceinline__ unsigned short f2bf(float f) {
    union { float f; unsigned u; } v; v.f = f;
    unsigned r = (v.u + 0x7FFFu + ((v.u >> 16) & 1u)) >> 16;
    return (unsigned short)r;
}
static __device__ __forceinline__ bf16x8 tobf(s16x8 s) {
    bf16x8 r; __builtin_memcpy(&r, &s, 16); return r;
}

// Prep: pack w1 (64x128 f32) into MFMA A-fragments (bf16), and transpose w2.
__global__ void prep(const float* __restrict__ w1, const float* __restrict__ w2,
                     uint4* __restrict__ af, float* __restrict__ w2t) {
    int idx = blockIdx.x * 256 + threadIdx.x;
    if (idx < 1024) {
        int lane = idx & 63, kb = (idx >> 6) & 3, ot = idx >> 8;
        int row   = ot * 16 + (lane & 15);
        int kbase = kb * 32 + ((lane >> 4) & 3) * 8;
        const float* src = w1 + row * Cn + kbase;
        unsigned short b[8];
        #pragma unroll
        for (int t = 0; t < 8; ++t) b[t] = f2bf(src[t]);
        uint4 r;
        r.x = (unsigned)b[0] | ((unsigned)b[1] << 16);
        r.y = (unsigned)b[2] | ((unsigned)b[3] << 16);
        r.z = (unsigned)b[4] | ((unsigned)b[5] << 16);
        r.w = (unsigned)b[6] | ((unsigned)b[7] << 16);
        af[idx] = r;
    } else if (idx < 1024 + ChN * 4) {
        int t = idx - 1024;               // t = o*4 + k
        w2t[t] = w2[(t & 3) * ChN + (t >> 2)];
    }
}

__device__ __forceinline__ float softplus_f(float x) {
    return fmaxf(x, 0.0f) + log1pf(expf(-fabsf(x)));
}

// ============================ Kernel A: w-field ============================
// MFMA 16x16x32 over 16-px chunks; 2 chunks per wave (loop) so waves live
// longer and the q=1 loads overlap the q=0 compute. SoA outputs.
__global__ __launch_bounds__(256) void wfield(
    const float* __restrict__ wi,
    const uint4* __restrict__ af,
    const float* __restrict__ w2t,
    const float* __restrict__ b1,
    const float* __restrict__ b2,
    float* __restrict__ wu_f, float* __restrict__ wd_f,
    float* __restrict__ wl_f, float* __restrict__ wr_f)
{
    const int tid  = threadIdx.x;
    const int wv   = tid >> 6;
    const int lane = tid & 63;
    const int l15  = lane & 15;
    const int lg   = lane >> 4;

    const int wid = blockIdx.x * 4 + wv;       // 0..16383

    for (int q = 0; q < 2; ++q) {
        const int chunk = wid * 2 + q;         // 0..32767
        const int p0    = chunk * 16;          // first pixel (b-i-j linear)
        const int bb    = p0 >> 16;            // batch
        const int rem   = p0 & (int)(HWn - 1); // i*Wn + j

        const float* wip = wi + (size_t)bb * CHWn + rem + l15;

        // All 32 channel-strided loads in flight before any dependent work.
        float xb[32];
        #pragma unroll
        for (int kb = 0; kb < 4; ++kb)
            #pragma unroll
            for (int t = 0; t < 8; ++t)
                xb[kb * 8 + t] = wip[(size_t)(kb * 32 + lg * 8 + t) * HWn];

        f32x4 acc[4];
        #pragma unroll
        for (int ot = 0; ot < 4; ++ot)
            acc[ot] = *(const f32x4*)(b1 + ot * 16 + lg * 4);   // b1 in C

        #pragma unroll
        for (int kb = 0; kb < 4; ++kb) {
            s16x8 bs;
            #pragma unroll
            for (int t = 0; t < 8; ++t) bs[t] = (short)f2bf(xb[kb * 8 + t]);
            bf16x8 bfrag = tobf(bs);
            #pragma unroll
            for (int ot = 0; ot < 4; ++ot) {
                s16x8 as = ((const s16x8*)af)[(ot * 4 + kb) * 64 + lane];
                acc[ot] = __builtin_amdgcn_mfma_f32_16x16x32_bf16(
                              tobf(as), bfrag, acc[ot], 0, 0, 0);
            }
        }

        float a0 = 0.f, a1 = 0.f, a2 = 0.f, a3 = 0.f;
        #pragma unroll
        for (int ot = 0; ot < 4; ++ot) {
            #pragma unroll
            for (int r = 0; r < 4; ++r) {
                int o = ot * 16 + lg * 4 + r;
                float hv = fmaxf(acc[ot][r], 0.f);
                const float4 w4v = ((const float4*)w2t)[o];
                a0 = fmaf(w4v.x, hv, a0);
                a1 = fmaf(w4v.y, hv, a1);
                a2 = fmaf(w4v.z, hv, a2);
                a3 = fmaf(w4v.w, hv, a3);
            }
        }
        a0 += __shfl_xor(a0, 16); a0 += __shfl_xor(a0, 32);
        a1 += __shfl_xor(a1, 16); a1 += __shfl_xor(a1, 32);
        a2 += __shfl_xor(a2, 16); a2 += __shfl_xor(a2, 32);
        a3 += __shfl_xor(a3, 16); a3 += __shfl_xor(a3, 32);

        if (lg == 0) {
            const int p = p0 + l15;
            wu_f[p] = softplus_f(a0 + b2[0]);
            wd_f[p] = softplus_f(a1 + b2[1]);
            wl_f[p] = softplus_f(a2 + b2[2]);
            wr_f[p] = softplus_f(a3 + b2[3]);
        }
    }
}

// ============================ Kernel B: stencil ============================
// Wave = 32-row column strip of one (b,c) plane, processed as a ROLLING
// window: per iteration 1 new u row + 4 w rows + 1 store (u halo reused in
// registers). 31-iter branch-free loop, unroll 4 -> continuously-fed load
// pipeline (m13-copy-like), unlike rounds 10/12's load-wait-store-die waves
// that plateaued at 2.3 TB/s. Grid = 8b x 128c x 2half = 2048 blocks
// (8/CU); blk&7 = batch = XCD partition.
__global__ __launch_bounds__(256) void stencil3(
    const float* __restrict__ u,
    const float* __restrict__ wu_f, const float* __restrict__ wd_f,
    const float* __restrict__ wl_f, const float* __restrict__ wr_f,
    float* __restrict__ out)
{
    const int bb   = blockIdx.x & 7;
    const int r0   = blockIdx.x >> 3;         // 0..255
    const int c    = r0 >> 1;                 // 0..127
    const int half = r0 & 1;
    const int wv   = threadIdx.x >> 6;
    const int lane = threadIdx.x & 63;

    const int i0 = (half * 4 + wv) * 32;      // first row of this wave's strip
    const int j4 = lane * 4;

    const size_t plane = ((size_t)bb * Cn + c) * HWn;
    const float* up0 = u   + plane + j4;
    float*       po  = out + plane + j4;
    const size_t wbo = (size_t)bb * HWn + j4;
    const float* wub = wu_f + wbo;
    const float* wdb = wd_f + wbo;
    const float* wlb = wl_f + wbo;
    const float* wrb = wr_f + wbo;

    const float4 z4 = {0.f, 0.f, 0.f, 0.f};

    float4 Rp = (i0 > 0) ? *(const float4*)(up0 + (size_t)(i0 - 1) * Wn) : z4;
    float4 Rc = *(const float4*)(up0 + (size_t)i0 * Wn);

    #pragma unroll 4
    for (int r = 0; r < 31; ++r) {
        const int i = i0 + r;                 // i+1 <= i0+31 <= 255: always valid
        float4 Rn = *(const float4*)(up0 + (size_t)(i + 1) * Wn);
        const size_t wo = (size_t)i * Wn;
        float4 WU = *(const float4*)(wub + wo);
        float4 WD = *(const float4*)(wdb + wo);
        float4 WL = *(const float4*)(wlb + wo);
        float4 WR = *(const float4*)(wrb + wo);

        float lw = __shfl(Rc.w, lane - 1);
        float rw = __shfl(Rc.x, lane + 1);
        float lfx = (lane == 0)  ? 0.f : lw;
        float rtw = (lane == 63) ? 0.f : rw;

        float4 WS;
        WS.x = (WU.x + WD.x) + (WL.x + WR.x);
        WS.y = (WU.y + WD.y) + (WL.y + WR.y);
        WS.z = (WU.z + WD.z) + (WL.z + WR.z);
        WS.w = (WU.w + WD.w) + (WL.w + WR.w);

        float4 res;
        res.x = fmaf(WU.x, Rp.x, fmaf(WD.x, Rn.x, fmaf(WL.x, lfx,  fmaf(WR.x, Rc.y, -WS.x * Rc.x))));
        res.y = fmaf(WU.y, Rp.y, fmaf(WD.y, Rn.y, fmaf(WL.y, Rc.x, fmaf(WR.y, Rc.z, -WS.y * Rc.y))));
        res.z = fmaf(WU.z, Rp.z, fmaf(WD.z, Rn.z, fmaf(WL.z, Rc.y, fmaf(WR.z, Rc.w, -WS.z * Rc.z))));
        res.w = fmaf(WU.w, Rp.w, fmaf(WD.w, Rn.w, fmaf(WL.w, Rc.z, fmaf(WR.w, rtw,  -WS.w * Rc.w))));
        *(float4*)(po + wo) = res;

        Rp = Rc; Rc = Rn;
    }

    // last row of the strip (r = 31): down-neighbor may be out of image
    {
        const int i = i0 + 31;
        float4 Rn = (i + 1 < Hn) ? *(const float4*)(up0 + (size_t)(i + 1) * Wn) : z4;
        const size_t wo = (size_t)i * Wn;
        float4 WU = *(const float4*)(wub + wo);
        float4 WD = *(const float4*)(wdb + wo);
        float4 WL = *(const float4*)(wlb + wo);
        float4 WR = *(const float4*)(wrb + wo);

        float lw = __shfl(Rc.w, lane - 1);
        float rw = __shfl(Rc.x, lane + 1);
        float lfx = (lane == 0)  ? 0.f : lw;
        float rtw = (lane == 63) ? 0.f : rw;

        float4 WS;
        WS.x = (WU.x + WD.x) + (WL.x + WR.x);
        WS.y = (WU.y + WD.y) + (WL.y + WR.y);
        WS.z = (WU.z + WD.z) + (WL.z + WR.z);
        WS.w = (WU.w + WD.w) + (WL.w + WR.w);

        float4 res;
        res.x = fmaf(WU.x, Rp.x, fmaf(WD.x, Rn.x, fmaf(WL.x, lfx,  fmaf(WR.x, Rc.y, -WS.x * Rc.x))));
        res.y = fmaf(WU.y, Rp.y, fmaf(WD.y, Rn.y, fmaf(WL.y, Rc.x, fmaf(WR.y, Rc.z, -WS.y * Rc.y))));
        res.z = fmaf(WU.z, Rp.z, fmaf(WD.z, Rn.z, fmaf(WL.z, Rc.y, fmaf(WR.z, Rc.w, -WS.z * Rc.z))));
        res.w = fmaf(WU.w, Rp.w, fmaf(WD.w, Rn.w, fmaf(WL.w, Rc.z, fmaf(WR.w, rtw,  -WS.w * Rc.w))));
        *(float4*)(po + wo) = res;
    }
}

extern "C" void kernel_launch(void* const* d_in, const int* in_sizes, int n_in,
                              void* d_out, int out_size, void* d_ws, size_t ws_size,
                              hipStream_t stream) {
    const float* u  = (const float*)d_in[0];
    const float* wi = (const float*)d_in[1];
    const float* w1 = (const float*)d_in[2];
    const float* b1 = (const float*)d_in[3];
    const float* w2 = (const float*)d_in[4];
    const float* b2 = (const float*)d_in[5];
    float* out = (float*)d_out;

    uint4* af  = (uint4*)d_ws;                       // 16 KB
    float* w2t = (float*)((char*)d_ws + 16384);      // 1 KB (pad to 17408)
    float* wu_f = (float*)((char*)d_ws + 17408);     // 4 x 2 MB SoA planes
    float* wd_f = wu_f + Bn * HWn;
    float* wl_f = wd_f + Bn * HWn;
    float* wr_f = wl_f + Bn * HWn;

    prep<<<5, 256, 0, stream>>>(w1, w2, af, w2t);
    wfield<<<4096, 256, 0, stream>>>(wi, af, w2t, b1, b2, wu_f, wd_f, wl_f, wr_f);
    stencil3<<<2048, 256, 0, stream>>>(u, wu_f, wd_f, wl_f, wr_f, out);
}

// Round 14
// 190.548 us; speedup vs baseline: 1.6305x; 1.3523x over previous
//
#include <hip/hip_runtime.h>
#include <math.h>

// Problem constants (B,C,H,W) = (8,128,256,256), Ch = 64
constexpr int Bn = 8, Cn = 128, ChN = 64, Hn = 256, Wn = 256;
constexpr long long HWn  = (long long)Hn * Wn;   // 65536
constexpr long long CHWn = (long long)Cn * HWn;  // 8388608

typedef short  s16x8  __attribute__((ext_vector_type(8)));
typedef __bf16 bf16x8 __attribute__((ext_vector_type(8)));
typedef float  f32x4  __attribute__((ext_vector_type(4)));

static __device__ __forceinline__ unsigned short f2bf(float f) {
    union { float f; unsigned u; } v; v.f = f;
    unsigned r = (v.u + 0x7FFFu + ((v.u >> 16) & 1u)) >> 16;
    return (unsigned short)r;
}
static __device__ __forceinline__ bf16x8 tobf(s16x8 s) {
    bf16x8 r; __builtin_memcpy(&r, &s, 16); return r;
}

// Prep: pack w1 (64x128 f32) into MFMA A-fragments (bf16), and transpose w2.
__global__ void prep(const float* __restrict__ w1, const float* __restrict__ w2,
                     uint4* __restrict__ af, float* __restrict__ w2t) {
    int idx = blockIdx.x * 256 + threadIdx.x;
    if (idx < 1024) {
        int lane = idx & 63, kb = (idx >> 6) & 3, ot = idx >> 8;
        int row   = ot * 16 + (lane & 15);
        int kbase = kb * 32 + ((lane >> 4) & 3) * 8;
        const float* src = w1 + row * Cn + kbase;
        unsigned short b[8];
        #pragma unroll
        for (int t = 0; t < 8; ++t) b[t] = f2bf(src[t]);
        uint4 r;
        r.x = (unsigned)b[0] | ((unsigned)b[1] << 16);
        r.y = (unsigned)b[2] | ((unsigned)b[3] << 16);
        r.z = (unsigned)b[4] | ((unsigned)b[5] << 16);
        r.w = (unsigned)b[6] | ((unsigned)b[7] << 16);
        af[idx] = r;
    } else if (idx < 1024 + ChN * 4) {
        int t = idx - 1024;               // t = o*4 + k
        w2t[t] = w2[(t & 3) * ChN + (t >> 2)];
    }
}

__device__ __forceinline__ float softplus_f(float x) {
    return fmaxf(x, 0.0f) + log1pf(expf(-fabsf(x)));
}

// ============================ Kernel A: w-field ============================
// MFMA 16x16x32 over 16-px chunks; 2 chunks per wave. Output layout is now
// PACKED per row: wpk[((b*Hn + i)*4 + dir)*Wn + j] -> an 8-row strip of all
// 4 dirs is 32 KB contiguous (one LDS-stage burst in the stencil).
__global__ __launch_bounds__(256) void wfield(
    const float* __restrict__ wi,
    const uint4* __restrict__ af,
    const float* __restrict__ w2t,
    const float* __restrict__ b1,
    const float* __restrict__ b2,
    float* __restrict__ wpk)
{
    const int tid  = threadIdx.x;
    const int wv   = tid >> 6;
    const int lane = tid & 63;
    const int l15  = lane & 15;
    const int lg   = lane >> 4;

    const int wid = blockIdx.x * 4 + wv;       // 0..16383

    for (int q = 0; q < 2; ++q) {
        const int chunk = wid * 2 + q;         // 0..32767
        const int p0    = chunk * 16;          // first pixel (b-i-j linear)
        const int bb    = p0 >> 16;            // batch
        const int rem   = p0 & (int)(HWn - 1); // i*Wn + j

        const float* wip = wi + (size_t)bb * CHWn + rem + l15;

        float xb[32];
        #pragma unroll
        for (int kb = 0; kb < 4; ++kb)
            #pragma unroll
            for (int t = 0; t < 8; ++t)
                xb[kb * 8 + t] = wip[(size_t)(kb * 32 + lg * 8 + t) * HWn];

        f32x4 acc[4];
        #pragma unroll
        for (int ot = 0; ot < 4; ++ot)
            acc[ot] = *(const f32x4*)(b1 + ot * 16 + lg * 4);   // b1 in C

        #pragma unroll
        for (int kb = 0; kb < 4; ++kb) {
            s16x8 bs;
            #pragma unroll
            for (int t = 0; t < 8; ++t) bs[t] = (short)f2bf(xb[kb * 8 + t]);
            bf16x8 bfrag = tobf(bs);
            #pragma unroll
            for (int ot = 0; ot < 4; ++ot) {
                s16x8 as = ((const s16x8*)af)[(ot * 4 + kb) * 64 + lane];
                acc[ot] = __builtin_amdgcn_mfma_f32_16x16x32_bf16(
                              tobf(as), bfrag, acc[ot], 0, 0, 0);
            }
        }

        float a0 = 0.f, a1 = 0.f, a2 = 0.f, a3 = 0.f;
        #pragma unroll
        for (int ot = 0; ot < 4; ++ot) {
            #pragma unroll
            for (int r = 0; r < 4; ++r) {
                int o = ot * 16 + lg * 4 + r;
                float hv = fmaxf(acc[ot][r], 0.f);
                const float4 w4v = ((const float4*)w2t)[o];
                a0 = fmaf(w4v.x, hv, a0);
                a1 = fmaf(w4v.y, hv, a1);
                a2 = fmaf(w4v.z, hv, a2);
                a3 = fmaf(w4v.w, hv, a3);
            }
        }
        a0 += __shfl_xor(a0, 16); a0 += __shfl_xor(a0, 32);
        a1 += __shfl_xor(a1, 16); a1 += __shfl_xor(a1, 32);
        a2 += __shfl_xor(a2, 16); a2 += __shfl_xor(a2, 32);
        a3 += __shfl_xor(a3, 16); a3 += __shfl_xor(a3, 32);

        if (lg == 0) {
            const int px = p0 + l15;
            const int i  = (px >> 8) & 255;
            const int j  = px & 255;
            float* wrow = wpk + ((size_t)(bb * Hn + i) * 4) * Wn + j;
            wrow[0 * Wn] = softplus_f(a0 + b2[0]);
            wrow[1 * Wn] = softplus_f(a1 + b2[1]);
            wrow[2 * Wn] = softplus_f(a2 + b2[2]);
            wrow[3 * Wn] = softplus_f(a3 + b2[3]);
        }
    }
}

// ============================ Kernel B: stencil ============================
// Copy-shaped: block = (b, 8-row strip, c-quarter). Stage the strip's packed
// w (32 KB) into LDS once (8 coalesced loads + 1 barrier). Each wave loops
// its 8 channels: 10 contiguous u-rows loaded upfront (10 KB in flight),
// 8 rows computed from registers + LDS-w, 8 KB stored. 2.4 vmem instr per
// output KB (was 6); 2 long contiguous streams per wave (was 6).
// Grid = 8 b x 32 strips x 4 cq = 1024; blk&7 = batch = XCD partition.
__global__ __launch_bounds__(256) void stencil5(
    const float* __restrict__ u,
    const float* __restrict__ wpk,
    float* __restrict__ out)
{
    const int bb    = blockIdx.x & 7;
    const int rest  = blockIdx.x >> 3;      // 0..127
    const int strip = rest & 31;            // 8-row strip
    const int cq    = rest >> 5;            // 0..3
    const int tid   = threadIdx.x;
    const int wv    = tid >> 6;
    const int lane  = tid & 63;

    const int i0 = strip * 8;
    const int c0 = cq * 32 + wv * 8;
    const int j4 = lane * 4;

    __shared__ float wlds[8 * 4 * 256];     // 32 KB: [r][dir][j]

    // stage: strip's packed w is 32 KB contiguous
    const float* wsrc = wpk + ((size_t)(bb * Hn + i0) * 4) * Wn;
    #pragma unroll
    for (int k = 0; k < 8; ++k) {
        f32x4 v = *(const f32x4*)(wsrc + (size_t)(k * 256 + tid) * 4);
        *(f32x4*)(wlds + (k * 256 + tid) * 4) = v;
    }
    __syncthreads();

    const float4 z4 = {0.f, 0.f, 0.f, 0.f};

    #pragma unroll 2
    for (int cc = 0; cc < 8; ++cc) {
        const int c = c0 + cc;
        const size_t plane = ((size_t)bb * Cn + c) * HWn;
        const float* up0 = u   + plane + j4;
        float*       po  = out + plane + j4;

        // 10 u-rows upfront: i0-1 .. i0+8 (boundary -> 0)
        float4 R[10];
        #pragma unroll
        for (int k = 0; k < 10; ++k) {
            const int i = i0 - 1 + k;
            R[k] = (i >= 0 && i < Hn) ? *(const float4*)(up0 + (size_t)i * Wn) : z4;
        }

        #pragma unroll
        for (int r = 0; r < 8; ++r) {
            float4 ctr = R[r + 1], up4 = R[r], dn4 = R[r + 2];
            const f32x4* wrow = (const f32x4*)(wlds + (size_t)(r * 4) * 256);
            f32x4 WU = wrow[0 * 64 + lane];
            f32x4 WD = wrow[1 * 64 + lane];
            f32x4 WL = wrow[2 * 64 + lane];
            f32x4 WR = wrow[3 * 64 + lane];

            float lw = __shfl(ctr.w, lane - 1);
            float rw = __shfl(ctr.x, lane + 1);
            float lfx = (lane == 0)  ? 0.f : lw;
            float rtw = (lane == 63) ? 0.f : rw;

            f32x4 WS = (WU + WD) + (WL + WR);

            f32x4 res;
            res[0] = fmaf(WU[0], up4.x, fmaf(WD[0], dn4.x, fmaf(WL[0], lfx,   fmaf(WR[0], ctr.y, -WS[0] * ctr.x))));
            res[1] = fmaf(WU[1], up4.y, fmaf(WD[1], dn4.y, fmaf(WL[1], ctr.x, fmaf(WR[1], ctr.z, -WS[1] * ctr.y))));
            res[2] = fmaf(WU[2], up4.z, fmaf(WD[2], dn4.z, fmaf(WL[2], ctr.y, fmaf(WR[2], ctr.w, -WS[2] * ctr.z))));
            res[3] = fmaf(WU[3], up4.w, fmaf(WD[3], dn4.w, fmaf(WL[3], ctr.z, fmaf(WR[3], rtw,   -WS[3] * ctr.w))));

            *(f32x4*)(po + (size_t)(i0 + r) * Wn) = res;
        }
    }
}

extern "C" void kernel_launch(void* const* d_in, const int* in_sizes, int n_in,
                              void* d_out, int out_size, void* d_ws, size_t ws_size,
                              hipStream_t stream) {
    const float* u  = (const float*)d_in[0];
    const float* wi = (const float*)d_in[1];
    const float* w1 = (const float*)d_in[2];
    const float* b1 = (const float*)d_in[3];
    const float* w2 = (const float*)d_in[4];
    const float* b2 = (const float*)d_in[5];
    float* out = (float*)d_out;

    uint4* af  = (uint4*)d_ws;                       // 16 KB
    float* w2t = (float*)((char*)d_ws + 16384);      // 1 KB (pad to 17408)
    float* wpk = (float*)((char*)d_ws + 17408);      // 8 MB packed w-field

    prep<<<5, 256, 0, stream>>>(w1, w2, af, w2t);
    wfield<<<4096, 256, 0, stream>>>(wi, af, w2t, b1, b2, wpk);
    stencil5<<<1024, 256, 0, stream>>>(u, wpk, out);
}